// Round 1
// baseline (289637.427 us; speedup 1.0000x reference)
//
#include <hip/hip_runtime.h>
#include <math.h>

#define TT 2048
#define BB 64
#define II 256
#define HH 512
#define EHD 128

__device__ __forceinline__ float dot4(const float4 a, const float4 b){
    return a.x*b.x + a.y*b.y + a.z*b.z + a.w*b.w;
}
__device__ __forceinline__ float sigm(float x){ return 1.0f/(1.0f+expf(-x)); }
__device__ __forceinline__ float leakyf(float x){ return x > 0.0f ? x : 0.01f*x; }
__device__ __forceinline__ float alphaf(float x){
    float p = 1.0f/(1.0f+expf(-x));
    return p/(1.0f-p);
}

// ---------------- encoder for h: one block = 4 rows ----------------
// smem needs 4*516 + 2*4*132 = 3120 floats
__device__ void enc_h_block(int e, const float* __restrict__ hsrc,
                            float* __restrict__ htil,
                            const float* __restrict__ w1, const float* __restrict__ b1,
                            const float* __restrict__ w2, const float* __restrict__ b2,
                            const float* __restrict__ w3, const float* __restrict__ b3,
                            float* smem)
{
    float* hlds = smem;              // [4][516]
    float* t1   = smem + 4*516;      // [4][132]
    float* t2   = t1 + 4*132;        // [4][132]
    const int tid = threadIdx.x;
    const int r0 = e * 4;
    for (int i = 0; i < 8; i++){
        int el = tid + i*256;
        int rr = el >> 9, k = el & 511;
        hlds[rr*516 + k] = hsrc[(r0+rr)*HH + k];
    }
    __syncthreads();
    const int cc = tid & 63;
    const int rr = (tid >> 6) & 3;
    // layer 1: 512 -> 128, leaky
    for (int cb = 0; cb < 2; cb++){
        int c = cc + cb*64;
        const float* wr = w1 + c*HH;
        const float* xr = hlds + rr*516;
        float acc = b1[c];
        #pragma unroll 4
        for (int k = 0; k < HH; k += 4)
            acc += dot4(*(const float4*)(xr+k), *(const float4*)(wr+k));
        t1[rr*132 + c] = leakyf(acc);
    }
    __syncthreads();
    // layer 2: 128 -> 128, leaky
    for (int cb = 0; cb < 2; cb++){
        int c = cc + cb*64;
        const float* wr = w2 + c*EHD;
        const float* xr = t1 + rr*132;
        float acc = b2[c];
        #pragma unroll 4
        for (int k = 0; k < EHD; k += 4)
            acc += dot4(*(const float4*)(xr+k), *(const float4*)(wr+k));
        t2[rr*132 + c] = leakyf(acc);
    }
    __syncthreads();
    // layer 3: 128 -> 512, alpha, scale by raw h
    for (int cb = 0; cb < 8; cb++){
        int c = cc + cb*64;
        const float* wr = w3 + c*EHD;
        const float* xr = t2 + rr*132;
        float acc = b3[c];
        #pragma unroll 4
        for (int k = 0; k < EHD; k += 4)
            acc += dot4(*(const float4*)(xr+k), *(const float4*)(wr+k));
        float a = alphaf(acc);
        htil[(r0+rr)*HH + c] = hlds[rr*516 + c] * a;
    }
}

__global__ __launch_bounds__(256) void enc_only_kernel(
    const float* __restrict__ hsrc, float* __restrict__ htil,
    const float* __restrict__ w1, const float* __restrict__ b1,
    const float* __restrict__ w2, const float* __restrict__ b2,
    const float* __restrict__ w3, const float* __restrict__ b3)
{
    __shared__ float smem[3120];
    enc_h_block(blockIdx.x, hsrc, htil, w1, b1, w2, b2, w3, b3, smem);
}

// ---------------- one LSTM phase: gates + pointwise (+ concurrent encoder) ----------------
// blocks 0..127: gates; blocks 128..143: encoder for the *other* layer's h.
__global__ __launch_bounds__(256) void step_kernel(
    const float* __restrict__ xsrc, long xstride, int Kx,
    const float* __restrict__ Wih, const float* __restrict__ Whh,
    const float* __restrict__ bih, const float* __restrict__ bhh,
    const float* __restrict__ htil_in, float* __restrict__ h_out,
    float* __restrict__ c_st,
    float* __restrict__ y_out, long ystride,
    const float* __restrict__ enc_src, float* __restrict__ enc_dst,
    const float* __restrict__ ew1, const float* __restrict__ eb1,
    const float* __restrict__ ew2, const float* __restrict__ eb2,
    const float* __restrict__ ew3, const float* __restrict__ eb3)
{
    __shared__ float smem[64*68 + 64*17];
    const int blk = blockIdx.x;
    if (blk >= 128){
        enc_h_block(blk - 128, enc_src, enc_dst, ew1, eb1, ew2, eb2, ew3, eb3, smem);
        return;
    }
    const int tid = threadIdx.x;
    float* xlds = smem;             // [64][68]
    float* glds = smem + 64*68;     // [64][17]
    const int j0 = blk * 4;
    const int ng = tid & 7;         // 8 n-groups (2 cols each)
    const int rg = tid >> 3;        // 32 row-groups (2 rows each)
    const int nl0 = ng*2, nl1 = nl0 + 1;                 // local col in [0,16): g*4+jj
    const int n0 = (nl0 >> 2)*HH + j0 + (nl0 & 3);       // absolute gate col
    const int n1 = (nl1 >> 2)*HH + j0 + (nl1 & 3);
    float a00 = bih[n0] + bhh[n0];
    float a01 = bih[n1] + bhh[n1];
    float a10 = a00, a11 = a01;

    const int klen = Kx + HH;
    for (int k0 = 0; k0 < klen; k0 += 64){
        // stage 64x64 activation chunk into LDS
        for (int i = 0; i < 16; i++){
            int el = tid + i*256;
            int kk = el & 63, r = el >> 6;
            int k = k0 + kk;
            float v = (k < Kx) ? xsrc[(long)r*xstride + k]
                               : htil_in[r*HH + (k - Kx)];
            xlds[r*68 + kk] = v;
        }
        __syncthreads();
        const float* w0p;
        const float* w1p;
        if (k0 < Kx){
            w0p = Wih + (long)n0*Kx + k0;
            w1p = Wih + (long)n1*Kx + k0;
        } else {
            w0p = Whh + (long)n0*HH + (k0 - Kx);
            w1p = Whh + (long)n1*HH + (k0 - Kx);
        }
        const float* x0 = xlds + (rg*2)*68;
        const float* x1 = x0 + 68;
        #pragma unroll 4
        for (int kk = 0; kk < 64; kk += 4){
            float4 xv0 = *(const float4*)(x0 + kk);
            float4 xv1 = *(const float4*)(x1 + kk);
            float4 wv0 = *(const float4*)(w0p + kk);
            float4 wv1 = *(const float4*)(w1p + kk);
            a00 += dot4(xv0, wv0);
            a01 += dot4(xv0, wv1);
            a10 += dot4(xv1, wv0);
            a11 += dot4(xv1, wv1);
        }
        __syncthreads();
    }
    // exchange gates through LDS so each thread gets (i,f,g,o) for one (b,j)
    const int r0 = rg * 2;
    glds[r0*17 + nl0]     = a00;
    glds[r0*17 + nl1]     = a01;
    glds[(r0+1)*17 + nl0] = a10;
    glds[(r0+1)*17 + nl1] = a11;
    __syncthreads();
    const int b  = tid >> 2;
    const int jj = tid & 3;
    float gi = glds[b*17 + 0*4 + jj];
    float gf = glds[b*17 + 1*4 + jj];
    float gg = glds[b*17 + 2*4 + jj];
    float go = glds[b*17 + 3*4 + jj];
    const int j = j0 + jj;
    float cold = c_st[b*HH + j];
    float cn = sigm(gf)*cold + sigm(gi)*tanhf(gg);
    float hn = sigm(go)*tanhf(cn);
    c_st[b*HH + j]  = cn;
    h_out[b*HH + j] = hn;
    if (y_out) y_out[(long)b*ystride + j] = hn;
}

// ---------------- x' = input * alpha_y(input), all B*T rows at once ----------------
__global__ __launch_bounds__(256) void ency_kernel(
    const float* __restrict__ xin, float* __restrict__ xprime,
    const float* __restrict__ w1, const float* __restrict__ b1,
    const float* __restrict__ w2, const float* __restrict__ b2,
    const float* __restrict__ w3, const float* __restrict__ b3)
{
    __shared__ float t1[32*128];
    __shared__ float t2[32*128];
    const long m0 = (long)blockIdx.x * 32;
    const int tid = threadIdx.x;
    const int cc = tid & 63;
    const int rr = tid >> 6;   // 0..3
    // layer 1: 256 -> 128 (x read straight from global; wave-uniform broadcast)
    for (int cb = 0; cb < 2; cb++){
        int c = cc + cb*64;
        const float* wr = w1 + c*II;
        for (int q = 0; q < 8; q++){
            int r = rr*8 + q;
            const float* xr = xin + (m0 + r)*II;
            float acc = b1[c];
            #pragma unroll 4
            for (int k = 0; k < II; k += 4)
                acc += dot4(*(const float4*)(xr+k), *(const float4*)(wr+k));
            t1[r*128 + c] = leakyf(acc);
        }
    }
    __syncthreads();
    // layer 2: 128 -> 128
    for (int cb = 0; cb < 2; cb++){
        int c = cc + cb*64;
        const float* wr = w2 + c*EHD;
        for (int q = 0; q < 8; q++){
            int r = rr*8 + q;
            const float* xr = t1 + r*128;
            float acc = b2[c];
            #pragma unroll 4
            for (int k = 0; k < EHD; k += 4)
                acc += dot4(*(const float4*)(xr+k), *(const float4*)(wr+k));
            t2[r*128 + c] = leakyf(acc);
        }
    }
    __syncthreads();
    // layer 3: 128 -> 256, alpha, x' = x * alpha
    for (int cb = 0; cb < 4; cb++){
        int c = cc + cb*64;
        const float* wr = w3 + c*EHD;
        for (int q = 0; q < 8; q++){
            int r = rr*8 + q;
            const float* xr = t2 + r*128;
            float acc = b3[c];
            #pragma unroll 4
            for (int k = 0; k < EHD; k += 4)
                acc += dot4(*(const float4*)(xr+k), *(const float4*)(wr+k));
            float a = alphaf(acc);
            xprime[(m0 + r)*II + c] = xin[(m0 + r)*II + c] * a;
        }
    }
}

__global__ __launch_bounds__(256) void init_state_kernel(
    const float* __restrict__ h0, const float* __restrict__ c0,
    float* __restrict__ h_st, float* __restrict__ c_st)
{
    int i = blockIdx.x*256 + threadIdx.x;   // 65536 total
    h_st[i] = h0[i];
    c_st[i] = c0[i];
}

__global__ __launch_bounds__(256) void epilogue_kernel(
    const float* __restrict__ h_st, const float* __restrict__ c_st,
    float* __restrict__ out_tail)
{
    int i = blockIdx.x*256 + threadIdx.x;   // 65536 total
    out_tail[i]         = h_st[i];
    out_tail[65536 + i] = c_st[i];
}

extern "C" void kernel_launch(void* const* d_in, const int* in_sizes, int n_in,
                              void* d_out, int out_size, void* d_ws, size_t ws_size,
                              hipStream_t stream)
{
    const float* input = (const float*)d_in[0];
    const float* h0in  = (const float*)d_in[1];
    const float* c0in  = (const float*)d_in[2];
    const float* Wih0  = (const float*)d_in[3];
    const float* Whh0  = (const float*)d_in[4];
    const float* bih0  = (const float*)d_in[5];
    const float* bhh0  = (const float*)d_in[6];
    const float* Wih1  = (const float*)d_in[7];
    const float* Whh1  = (const float*)d_in[8];
    const float* bih1  = (const float*)d_in[9];
    const float* bhh1  = (const float*)d_in[10];
    const float* eyw1  = (const float*)d_in[11];
    const float* eyb1  = (const float*)d_in[12];
    const float* eyw2  = (const float*)d_in[13];
    const float* eyb2  = (const float*)d_in[14];
    const float* eyw3  = (const float*)d_in[15];
    const float* eyb3  = (const float*)d_in[16];
    const float* ehw1  = (const float*)d_in[17];
    const float* ehb1  = (const float*)d_in[18];
    const float* ehw2  = (const float*)d_in[19];
    const float* ehb2  = (const float*)d_in[20];
    const float* ehw3  = (const float*)d_in[21];
    const float* ehb3  = (const float*)d_in[22];

    float* out = (float*)d_out;
    float* ws  = (float*)d_ws;

    float* xprime = ws;                            // B*T*I = 33,554,432 floats
    float* h_st   = ws + 33554432;                 // [2][64][512]
    float* c_st   = h_st + 65536;                  // [2][64][512]
    float* htil   = c_st + 65536;                  // [2][64][512] (h * alpha_h)
    float* h0_st  = h_st;
    float* h1_st  = h_st + 32768;
    float* c0_st  = c_st;
    float* c1_st  = c_st + 32768;
    float* htil0  = htil;
    float* htil1  = htil + 32768;

    init_state_kernel<<<256, 256, 0, stream>>>(h0in, c0in, h_st, c_st);
    ency_kernel<<<4096, 256, 0, stream>>>(input, xprime,
                                          eyw1, eyb1, eyw2, eyb2, eyw3, eyb3);
    // prologue: htil0 from initial h0
    enc_only_kernel<<<16, 256, 0, stream>>>(h0_st, htil0,
                                            ehw1, ehb1, ehw2, ehb2, ehw3, ehb3);

    const long xstride0 = (long)TT * II;
    const long ystride  = (long)TT * HH;
    for (int t = 0; t < TT; t++){
        // P1: layer-0 LSTM; concurrently h~1 = enc(h1_{t-1})
        step_kernel<<<144, 256, 0, stream>>>(
            xprime + (long)t*II, xstride0, II,
            Wih0, Whh0, bih0, bhh0,
            htil0, h0_st, c0_st,
            nullptr, 0,
            h1_st, htil1,
            ehw1, ehb1, ehw2, ehb2, ehw3, ehb3);
        // P2: layer-1 LSTM + y_t; concurrently h~0 = enc(h0_t) for next step
        step_kernel<<<144, 256, 0, stream>>>(
            h0_st, (long)HH, HH,
            Wih1, Whh1, bih1, bhh1,
            htil1, h1_st, c1_st,
            out + (long)t*HH, ystride,
            h0_st, htil0,
            ehw1, ehb1, ehw2, ehb2, ehw3, ehb3);
    }
    epilogue_kernel<<<256, 256, 0, stream>>>(h_st, c_st,
                                             out + (long)BB*TT*HH);
}